// Round 14
// baseline (296.408 us; speedup 1.0000x reference)
//
#include <hip/hip_runtime.h>
#include <hip/hip_bf16.h>

// ---------------------------------------------------------------------------
// GraphSAGE 3-layer + global mean pool, fp32 in/out.
//   layer: agg = mean_{e:dst=n} relu(h[src_e]);  h' = agg@Wl^T + bl + h@Wr^T
// R1-R14: 810 -> 336us. R15 coop frontend REGRESSED. R16 neutral.
// R17/18 agg40 ILP -> 326.8. R19 csr_offsets -> 325. R20 neutral.
// R21 layer1+2 fuse. R22-R25 tile/TLP/barrier probes ~neutral.
// R26: fragment-linear weight packing (B loads were 16-way line-amplified):
//   325 -> 293.3us. Request-rate was the GEMM stall all along.
// R27: sage0 ported to BM=32 barrier-minimal: NEUTRAL (294.4) -> GEMMs done.
// R28 (this round): overlap deg atomics under x-conversion BW. deg_kernel
//   becomes xconv_deg (x->xb convert + edge atomics in one big-grid
//   launch; deg zeroed in prior init dispatch -> no race). init shrinks
//   to weights/zeros/gstart. Same dispatch count, pure latency-hiding.
//   Predict 293 -> ~286-290. If neutral: all kernels at measured floors.
// ---------------------------------------------------------------------------

#define NODES 50000
#define K_DIM 128
#define N_GRAPHS 128

typedef __attribute__((ext_vector_type(8))) short short8;
typedef __attribute__((ext_vector_type(4))) short short4v;
typedef __attribute__((ext_vector_type(4))) float f32x4;

__device__ inline short f2bf(float f) {
    unsigned u = __builtin_bit_cast(unsigned, f);
    u += 0x7FFFu + ((u >> 16) & 1u);          // RNE
    return (short)(u >> 16);
}
__device__ inline float bf2f(short h) {
    unsigned u = ((unsigned)(unsigned short)h) << 16;
    return __builtin_bit_cast(float, u);
}
__device__ inline float blo(unsigned u) { return __builtin_bit_cast(float, u << 16); }
__device__ inline float bhi(unsigned u) { return __builtin_bit_cast(float, u & 0xFFFF0000u); }
// pack: bits[15:0]=hi bf16, bits[31:16]=lo bf16
__device__ inline unsigned hilo_pack(float f) {
    short h = f2bf(f);
    short l = f2bf(f - bf2f(h));
    return ((unsigned)(unsigned short)h) | (((unsigned)(unsigned short)l) << 16);
}

// ------ init (small): zero deg+gsum+counter + FRAGMENT-PACKED wconv + gstart
// Phase-1 planes (4x 128x128): packed idx = ((wave*2+nt)*4+kc)*512 +
//   lane*8 + e  with n=wave*32+nt*16+(lane&15), k=kc*32+(lane>>4)*8+e.
// W2 plane (12288): packed idx = (nt2*4+kc)*512 + lane*8 + e, tiles 20..23
//   zero-padded; n=nt2*16+(lane&15) (<80), same k formula.
__global__ void init_kernel(const float* __restrict__ w0, const float* __restrict__ w1,
                            const float* __restrict__ w2, const float* __restrict__ w3,
                            const float* __restrict__ w4, const float* __restrict__ w5,
                            short* __restrict__ whi, short* __restrict__ wlo,
                            int* __restrict__ deg, const int* __restrict__ batch,
                            int* __restrict__ gstart, int* __restrict__ counter,
                            float* __restrict__ gsum, int N) {
    int idx = blockIdx.x * 256 + threadIdx.x;
    if (idx < N) deg[idx] = 0;
    if (idx < N_GRAPHS * 40) gsum[idx] = 0.f;
    if (idx == 0) *counter = 0;
    const int TOT = 4 * 16384 + 96 * 128;   // 77824
    if (idx < TOT) {
        float v;
        if (idx < 65536) {
            int m = idx >> 14, i2 = idx & 16383;
            const float* W = (m == 0) ? w0 : (m == 1) ? w1 : (m == 2) ? w2 : w3;
            int t1 = i2 >> 9, rem = i2 & 511;
            int lane = rem >> 3, e = rem & 7;
            int wv_ = t1 >> 3, nt = (t1 >> 2) & 1, kc = t1 & 3;
            int quad = lane >> 4, l15 = lane & 15;
            int n = wv_ * 32 + nt * 16 + l15;
            int k = kc * 32 + quad * 8 + e;
            v = W[n * 128 + k];
        } else {
            int i2 = idx - 65536;            // 0..12287
            int t2 = i2 >> 9, rem = i2 & 511;
            int lane = rem >> 3, e = rem & 7;
            int nt2 = t2 >> 2, kc = t2 & 3;
            int quad = lane >> 4, l15 = lane & 15;
            int n = nt2 * 16 + l15;
            int k = kc * 32 + quad * 8 + e;
            if (t2 < 20) {
                v = (n < 40) ? w4[n * 128 + k] : w5[(n - 40) * 128 + k];
            } else {
                v = 0.f;
            }
        }
        unsigned p = hilo_pack(v);
        whi[idx] = (short)(p & 0xFFFFu);
        wlo[idx] = (short)(p >> 16);
    }
    if (idx <= N_GRAPHS) {
        int g = idx;
        int lo = 0, hi = N;
        while (lo < hi) {
            int mid = (lo + hi) >> 1;
            if (batch[mid] < g) lo = mid + 1; else hi = mid;
        }
        gstart[g] = lo;
    }
}

// ------ xconv + deg: x->xb=bf16(relu(x)) (BW) ∥ edge deg atomics (latency) -
// deg zeroed in the prior init dispatch -> no intra-kernel race.
__global__ void xconv_deg(const float* __restrict__ x, short* __restrict__ xb,
                          const int* __restrict__ dst, int* __restrict__ deg,
                          int N, int E) {
    int idx = blockIdx.x * 256 + threadIdx.x;
    if (idx < E) atomicAdd(&deg[dst[idx]], 1);
    if (idx < N * (K_DIM / 4)) {
        float4 v = reinterpret_cast<const float4*>(x)[idx];
        short4v b;
        b[0] = f2bf(fmaxf(v.x, 0.f));
        b[1] = f2bf(fmaxf(v.y, 0.f));
        b[2] = f2bf(fmaxf(v.z, 0.f));
        b[3] = f2bf(fmaxf(v.w, 0.f));
        *reinterpret_cast<short4v*>(&xb[idx * 4]) = b;
    }
}

// single-dispatch offsets: block-local scan + atomic global base.
__global__ void csr_offsets(const int* __restrict__ deg, int* __restrict__ counter,
                            int* __restrict__ rowptr, int* __restrict__ fillpos, int N) {
    const int tid = threadIdx.x, lane = tid & 63, wv = tid >> 6;
    int i = blockIdx.x * 256 + tid;
    int v = (i < N) ? deg[i] : 0;
    int incl = v;
    #pragma unroll
    for (int off = 1; off < 64; off <<= 1) {
        int t = __shfl_up(incl, off, 64);
        if (lane >= off) incl += t;
    }
    __shared__ int ws[4];
    __shared__ int sbase;
    if (lane == 63) ws[wv] = incl;
    __syncthreads();
    if (tid == 0) sbase = atomicAdd(counter, ws[0] + ws[1] + ws[2] + ws[3]);
    __syncthreads();
    int add = sbase;
    for (int k = 0; k < wv; ++k) add += ws[k];
    int excl = add + incl - v;
    if (i < N) { rowptr[i] = excl; fillpos[i] = excl; }
}

__global__ void fill_kernel(const int* __restrict__ src, const int* __restrict__ dst,
                            int* __restrict__ fillpos, int* __restrict__ csr_src, int E) {
    int e = blockIdx.x * blockDim.x + threadIdx.x;
    if (e < E) {
        int p = atomicAdd(&fillpos[dst[e]], 1);
        csr_src[p] = src[e];
    }
}

// ------- aggregation from bf16 table (128-dim) -> bf16 mean ----------------
__global__ void agg_bf16(const unsigned short* __restrict__ hb,
                         const int* __restrict__ rowptr, const int* __restrict__ deg,
                         const int* __restrict__ csr_src,
                         short* __restrict__ aggb, int N) {
    int w = (blockIdx.x * blockDim.x + threadIdx.x) >> 6;
    if (w >= N) return;
    int lane = threadIdx.x & 63;
    int slot = lane >> 4, l16 = lane & 15;
    int s = rowptr[w];
    int e = s + deg[w];
    const uint4* T = reinterpret_cast<const uint4*>(hb);   // 16 uint4 per row
    float2 a0 = make_float2(0.f, 0.f), a1 = a0, a2 = a0, a3 = a0;
    int i = s + slot;
    for (; i + 4 < e; i += 8) {
        uint4 va = T[(size_t)csr_src[i] * 16 + l16];
        uint4 vb = T[(size_t)csr_src[i + 4] * 16 + l16];
        a0.x += blo(va.x) + blo(vb.x); a0.y += bhi(va.x) + bhi(vb.x);
        a1.x += blo(va.y) + blo(vb.y); a1.y += bhi(va.y) + bhi(vb.y);
        a2.x += blo(va.z) + blo(vb.z); a2.y += bhi(va.z) + bhi(vb.z);
        a3.x += blo(va.w) + blo(vb.w); a3.y += bhi(va.w) + bhi(vb.w);
    }
    for (; i < e; i += 4) {
        uint4 va = T[(size_t)csr_src[i] * 16 + l16];
        a0.x += blo(va.x); a0.y += bhi(va.x);
        a1.x += blo(va.y); a1.y += bhi(va.y);
        a2.x += blo(va.z); a2.y += bhi(va.z);
        a3.x += blo(va.w); a3.y += bhi(va.w);
    }
    #pragma unroll
    for (int off = 16; off <= 32; off <<= 1) {
        a0.x += __shfl_xor(a0.x, off, 64); a0.y += __shfl_xor(a0.y, off, 64);
        a1.x += __shfl_xor(a1.x, off, 64); a1.y += __shfl_xor(a1.y, off, 64);
        a2.x += __shfl_xor(a2.x, off, 64); a2.y += __shfl_xor(a2.y, off, 64);
        a3.x += __shfl_xor(a3.x, off, 64); a3.y += __shfl_xor(a3.y, off, 64);
    }
    if (slot == 0) {
        float inv = 1.0f / fmaxf((float)(e - s), 1.0f);
        short8 b;
        b[0] = f2bf(a0.x * inv); b[1] = f2bf(a0.y * inv);
        b[2] = f2bf(a1.x * inv); b[3] = f2bf(a1.y * inv);
        b[4] = f2bf(a2.x * inv); b[5] = f2bf(a2.y * inv);
        b[6] = f2bf(a3.x * inv); b[7] = f2bf(a3.y * inv);
        *reinterpret_cast<short8*>(&aggb[(size_t)w * K_DIM + l16 * 8]) = b;
    }
}

// --------- layer-0 MFMA GEMM: BM=32 barrier-minimal, packed B --------------
__global__ __launch_bounds__(256) void sage0_mfma(
        const short* __restrict__ Ab_in, const float* __restrict__ Xf,
        const short* __restrict__ Bhl, const short* __restrict__ Bll,
        const short* __restrict__ Bhr, const short* __restrict__ Blr,
        const float* __restrict__ bl,
        short* __restrict__ outHi, short* __restrict__ outLo, int N) {
    constexpr int BM = 32;
    constexpr int LSTA = 136;    // full-K row stride (shorts), 272B
    const int tid = threadIdx.x;
    const int lane = tid & 63;
    const int wave = tid >> 6;
    const int l15 = lane & 15;
    const int quad = lane >> 4;
    const int m0 = blockIdx.x * BM;

    __shared__ __align__(16) short SH[3 * BM * LSTA];   // 25.5 KB
    short* AbL = SH;
    short* AhL = SH + BM * LSTA;
    short* AlL = SH + 2 * BM * LSTA;

    f32x4 acc[2][2];
    #pragma unroll
    for (int i = 0; i < 2; ++i)
        #pragma unroll
        for (int j = 0; j < 2; ++j) acc[i][j] = (f32x4){0.f, 0.f, 0.f, 0.f};

    const short8 zero8 = (short8){0, 0, 0, 0, 0, 0, 0, 0};

    // ---- stage: ALL of A (aggb + packed(x) 32x128 each) in one shot ----
    {
        const int srow = tid >> 3;          // 0..31
        const int c0 = (tid & 7) * 16;      // 0,16,...,112
        const int sm = m0 + srow;
        short8 a0 = zero8, a1 = zero8, h0 = zero8, h1 = zero8, l0 = zero8, l1 = zero8;
        if (sm < N) {
            const short* pa = Ab_in + (size_t)sm * K_DIM + c0;
            a0 = *reinterpret_cast<const short8*>(pa);
            a1 = *reinterpret_cast<const short8*>(pa + 8);
            const float* xp = Xf + (size_t)sm * K_DIM + c0;
            float4 f0 = *reinterpret_cast<const float4*>(xp);
            float4 f1 = *reinterpret_cast<const float4*>(xp + 4);
            float4 f2 = *reinterpret_cast<const float4*>(xp + 8);
            float4 f3 = *reinterpret_cast<const float4*>(xp + 12);
            float fv[16] = {f0.x, f0.y, f0.z, f0.w, f1.x, f1.y, f1.z, f1.w,
                            f2.x, f2.y, f2.z, f2.w, f3.x, f3.y, f3.z, f3.w};
            #pragma unroll
            for (int j = 0; j < 8; ++j) {
                unsigned p = hilo_pack(fv[j]);
                h0[j] = (short)(p & 0xFFFFu);
                l0[j] = (short)(p >> 16);
            }
            #pragma unroll
            for (int j = 0; j < 8; ++j) {
                unsigned p = hilo_pack(fv[8 + j]);
                h1[j] = (short)(p & 0xFFFFu);
                l1[j] = (short)(p >> 16);
            }
        }
        *reinterpret_cast<short8*>(&AbL[srow * LSTA + c0])     = a0;
        *reinterpret_cast<short8*>(&AbL[srow * LSTA + c0 + 8]) = a1;
        *reinterpret_cast<short8*>(&AhL[srow * LSTA + c0])     = h0;
        *reinterpret_cast<short8*>(&AhL[srow * LSTA + c0 + 8]) = h1;
        *reinterpret_cast<short8*>(&AlL[srow * LSTA + c0])     = l0;
        *reinterpret_cast<short8*>(&AlL[srow * LSTA + c0 + 8]) = l1;
    }
    __syncthreads();

    // ---- 4 unfenced k-steps, packed B (1KB coalesced wave-loads) ----
    #pragma unroll
    for (int kc = 0; kc < 4; ++kc) {
        const int k0 = kc * 32;
        short8 bhl_[2], bll_[2], bhr_[2], blr_[2];
        #pragma unroll
        for (int nt = 0; nt < 2; ++nt) {
            size_t base = ((size_t)(((wave * 2 + nt) * 4 + kc) * 64 + lane)) * 8;
            bhl_[nt] = *reinterpret_cast<const short8*>(Bhl + base);
            bll_[nt] = *reinterpret_cast<const short8*>(Bll + base);
            bhr_[nt] = *reinterpret_cast<const short8*>(Bhr + base);
            blr_[nt] = *reinterpret_cast<const short8*>(Blr + base);
        }
        #pragma unroll
        for (int mt = 0; mt < 2; ++mt) {
            int row = mt * 16 + l15;
            short8 ab = *reinterpret_cast<const short8*>(&AbL[row * LSTA + k0 + quad * 8]);
            short8 ah = *reinterpret_cast<const short8*>(&AhL[row * LSTA + k0 + quad * 8]);
            short8 ao = *reinterpret_cast<const short8*>(&AlL[row * LSTA + k0 + quad * 8]);
            #pragma unroll
            for (int nt = 0; nt < 2; ++nt) {
                acc[mt][nt] = __builtin_amdgcn_mfma_f32_16x16x32_bf16(ab, bhl_[nt], acc[mt][nt], 0, 0, 0);
                acc[mt][nt] = __builtin_amdgcn_mfma_f32_16x16x32_bf16(ab, bll_[nt], acc[mt][nt], 0, 0, 0);
                acc[mt][nt] = __builtin_amdgcn_mfma_f32_16x16x32_bf16(ah, bhr_[nt], acc[mt][nt], 0, 0, 0);
                acc[mt][nt] = __builtin_amdgcn_mfma_f32_16x16x32_bf16(ah, blr_[nt], acc[mt][nt], 0, 0, 0);
                acc[mt][nt] = __builtin_amdgcn_mfma_f32_16x16x32_bf16(ao, bhr_[nt], acc[mt][nt], 0, 0, 0);
            }
        }
    }

    // ---- epilogue: relu(acc + bias) -> h1 hi/lo planes (global) ----
    #pragma unroll
    for (int mt = 0; mt < 2; ++mt) {
        #pragma unroll
        for (int nt = 0; nt < 2; ++nt) {
            int col = wave * 32 + nt * 16 + l15;
            float b = bl[col];
            #pragma unroll
            for (int reg = 0; reg < 4; ++reg) {
                int row = m0 + mt * 16 + quad * 4 + reg;
                if (row < N) {
                    float v = fmaxf(acc[mt][nt][reg] + b, 0.f);
                    unsigned p = hilo_pack(v);
                    outHi[(size_t)row * K_DIM + col] = (short)(p & 0xFFFFu);
                    outLo[(size_t)row * K_DIM + col] = (short)(p >> 16);
                }
            }
        }
    }
}

// --------- fused layer-1 + layer-2 GEMM (R26 form, measured-good) ---------
__global__ __launch_bounds__(256) void sage1_gemm80(
        const short* __restrict__ Ab_in,
        const short* __restrict__ Hhi_in, const short* __restrict__ Hlo_in,
        const short* __restrict__ Bhl, const short* __restrict__ Bll,
        const short* __restrict__ Bhr, const short* __restrict__ Blr,
        const float* __restrict__ bl,
        const short* __restrict__ B2h, const short* __restrict__ B2l,
        const float* __restrict__ b2,
        short* __restrict__ ylb, float* __restrict__ yr40, int N) {
    constexpr int BM = 32;
    constexpr int LSTA = 136;    // full-K row stride (shorts), 272B
    const int tid = threadIdx.x;
    const int lane = tid & 63;
    const int wave = tid >> 6;
    const int l15 = lane & 15;
    const int quad = lane >> 4;
    const int m0 = blockIdx.x * BM;

    __shared__ __align__(16) short SH[3 * BM * LSTA];   // 25.5 KB
    short* AbL = SH;
    short* AhL = SH + BM * LSTA;
    short* AlL = SH + 2 * BM * LSTA;
    // aliased after phase 1:
    short* H2h = SH;
    short* H2l = SH + BM * LSTA;

    f32x4 acc[2][2];
    #pragma unroll
    for (int i = 0; i < 2; ++i)
        #pragma unroll
        for (int j = 0; j < 2; ++j) acc[i][j] = (f32x4){0.f, 0.f, 0.f, 0.f};

    const short8 zero8 = (short8){0, 0, 0, 0, 0, 0, 0, 0};

    // ---- stage: ALL of A (3 planes x 32x128) in one shot ----
    {
        const int srow = tid >> 3;          // 0..31
        const int c0 = (tid & 7) * 16;      // 0,16,...,112
        const int sm = m0 + srow;
        short8 a0 = zero8, a1 = zero8, h0 = zero8, h1 = zero8, l0 = zero8, l1 = zero8;
        if (sm < N) {
            const short* pa = Ab_in  + (size_t)sm * K_DIM + c0;
            const short* ph = Hhi_in + (size_t)sm * K_DIM + c0;
            const short* pl = Hlo_in + (size_t)sm * K_DIM + c0;
            a0 = *reinterpret_cast<const short8*>(pa);
            a1 = *reinterpret_cast<const short8*>(pa + 8);
            h0 = *reinterpret_cast<const short8*>(ph);
            h1 = *reinterpret_cast<const short8*>(ph + 8);
            l0 = *reinterpret_cast<const short8*>(pl);
            l1 = *reinterpret_cast<const short8*>(pl + 8);
        }
        *reinterpret_cast<short8*>(&AbL[srow * LSTA + c0])     = a0;
        *reinterpret_cast<short8*>(&AbL[srow * LSTA + c0 + 8]) = a1;
        *reinterpret_cast<short8*>(&AhL[srow * LSTA + c0])     = h0;
        *reinterpret_cast<short8*>(&AhL[srow * LSTA + c0 + 8]) = h1;
        *reinterpret_cast<short8*>(&AlL[srow * LSTA + c0])     = l0;
        *reinterpret_cast<short8*>(&AlL[srow * LSTA + c0 + 8]) = l1;
    }
    __syncthreads();   // [1]

    // ---- phase 1: 4 unfenced k-steps, packed B (coalesced) ----
    #pragma unroll
    for (int kc = 0; kc < 4; ++kc) {
        const int k0 = kc * 32;
        short8 bhl_[2], bll_[2], bhr_[2], blr_[2];
        #pragma unroll
        for (int nt = 0; nt < 2; ++nt) {
            size_t base = ((size_t)(((wave * 2 + nt) * 4 + kc) * 64 + lane)) * 8;
            bhl_[nt] = *reinterpret_cast<const short8*>(Bhl + base);
            bll_[nt] = *reinterpret_cast<const short8*>(Bll + base);
            bhr_[nt] = *reinterpret_cast<const short8*>(Bhr + base);
            blr_[nt] = *reinterpret_cast<const short8*>(Blr + base);
        }
        #pragma unroll
        for (int mt = 0; mt < 2; ++mt) {
            int row = mt * 16 + l15;
            short8 ab = *reinterpret_cast<const short8*>(&AbL[row * LSTA + k0 + quad * 8]);
            short8 ah = *reinterpret_cast<const short8*>(&AhL[row * LSTA + k0 + quad * 8]);
            short8 ao = *reinterpret_cast<const short8*>(&AlL[row * LSTA + k0 + quad * 8]);
            #pragma unroll
            for (int nt = 0; nt < 2; ++nt) {
                acc[mt][nt] = __builtin_amdgcn_mfma_f32_16x16x32_bf16(ab, bhl_[nt], acc[mt][nt], 0, 0, 0);
                acc[mt][nt] = __builtin_amdgcn_mfma_f32_16x16x32_bf16(ab, bll_[nt], acc[mt][nt], 0, 0, 0);
                acc[mt][nt] = __builtin_amdgcn_mfma_f32_16x16x32_bf16(ah, bhr_[nt], acc[mt][nt], 0, 0, 0);
                acc[mt][nt] = __builtin_amdgcn_mfma_f32_16x16x32_bf16(ah, blr_[nt], acc[mt][nt], 0, 0, 0);
                acc[mt][nt] = __builtin_amdgcn_mfma_f32_16x16x32_bf16(ao, bhr_[nt], acc[mt][nt], 0, 0, 0);
            }
        }
    }

    __syncthreads();   // [2] all phase-1 LDS reads done; A buffer now dead

    // ---- h2 = relu(acc+bias) -> LDS (aliased), full 32x128 ----
    #pragma unroll
    for (int mt = 0; mt < 2; ++mt) {
        #pragma unroll
        for (int nt = 0; nt < 2; ++nt) {
            int col = wave * 32 + nt * 16 + l15;
            float b = bl[col];
            #pragma unroll
            for (int reg = 0; reg < 4; ++reg) {
                int row = mt * 16 + quad * 4 + reg;
                float v = fmaxf(acc[mt][nt][reg] + b, 0.f);
                unsigned p = hilo_pack(v);
                H2h[row * LSTA + col] = (short)(p & 0xFFFFu);
                H2l[row * LSTA + col] = (short)(p >> 16);
            }
        }
    }
    __syncthreads();   // [3]

    // ---- phase 2: 4 unfenced kc-steps from H2, packed B2 ----
    const int rg = wave >> 1, ch = wave & 1;
    const int NT = ch ? 2 : 3;
    const int ntb = ch ? 3 : 0;
    f32x4 c2[3];
    #pragma unroll
    for (int j = 0; j < 3; ++j) c2[j] = (f32x4){0.f, 0.f, 0.f, 0.f};
    const int arow = rg * 16 + l15;

    #pragma unroll
    for (int kc = 0; kc < 4; ++kc) {
        const int k0 = kc * 32;
        short8 ah = *reinterpret_cast<const short8*>(&H2h[arow * LSTA + k0 + quad * 8]);
        short8 ao = *reinterpret_cast<const short8*>(&H2l[arow * LSTA + k0 + quad * 8]);
        for (int j = 0; j < NT; ++j) {
            size_t base = ((size_t)(((ntb + j) * 4 + kc) * 64 + lane)) * 8;
            short8 bh = *reinterpret_cast<const short8*>(B2h + base);
            short8 bo = *reinterpret_cast<const short8*>(B2l + base);
            c2[j] = __builtin_amdgcn_mfma_f32_16x16x32_bf16(ah, bh, c2[j], 0, 0, 0);
            c2[j] = __builtin_amdgcn_mfma_f32_16x16x32_bf16(ah, bo, c2[j], 0, 0, 0);
            c2[j] = __builtin_amdgcn_mfma_f32_16x16x32_bf16(ao, bh, c2[j], 0, 0, 0);
        }
    }

    // ---- epilogue 2: ylb (cols 0-39, bf16), yr40 (cols 40-79, +bias) ----
    for (int j = 0; j < NT; ++j) {
        int col = (ntb + j) * 16 + l15;
        #pragma unroll
        for (int reg = 0; reg < 4; ++reg) {
            int row = m0 + rg * 16 + quad * 4 + reg;
            if (row < N) {
                float v = c2[j][reg];
                if (col < 40) {
                    ylb[(size_t)row * 40 + col] = f2bf(v);
                } else {
                    yr40[(size_t)row * 40 + (col - 40)] = v + b2[col - 40];
                }
            }
        }
    }
}

// ------- agg40 + pool: out[n] = mean_e ylb[src_e] + yr40[n];
//         gsum[g] += out[n]/cnt(g). --------------------------------------
__global__ __launch_bounds__(256) void agg40_pool(
        const unsigned int* __restrict__ ylbu, const float* __restrict__ yr40,
        const int* __restrict__ rowptr, const int* __restrict__ deg,
        const int* __restrict__ csr_src,
        const int* __restrict__ batch, const int* __restrict__ gstart,
        float* __restrict__ out, float* __restrict__ gsum, int N) {
    const int w = (blockIdx.x * blockDim.x + threadIdx.x) >> 6;
    const int lane = threadIdx.x & 63;
    const int wv = threadIdx.x >> 6;
    const int half = lane >> 5, l32 = lane & 31;
    __shared__ float sh[4][40];
    __shared__ int sg[4];
    __shared__ float sinv[4];

    if (w < N) {
        int s = rowptr[w], e = s + deg[w];
        float ax = 0.f, ay = 0.f;
        if (l32 < 20) {
            int i = s + half;
            for (; i + 6 < e; i += 8) {
                int s0 = csr_src[i], s1 = csr_src[i + 2], s2 = csr_src[i + 4], s3 = csr_src[i + 6];
                unsigned v0 = ylbu[(size_t)s0 * 20 + l32];
                unsigned v1 = ylbu[(size_t)s1 * 20 + l32];
                unsigned v2 = ylbu[(size_t)s2 * 20 + l32];
                unsigned v3 = ylbu[(size_t)s3 * 20 + l32];
                ax += (blo(v0) + blo(v1)) + (blo(v2) + blo(v3));
                ay += (bhi(v0) + bhi(v1)) + (bhi(v2) + bhi(v3));
            }
            for (; i < e; i += 2) {
                unsigned v0 = ylbu[(size_t)csr_src[i] * 20 + l32];
                ax += blo(v0); ay += bhi(v0);
            }
        }
        ax += __shfl_xor(ax, 32, 64);
        ay += __shfl_xor(ay, 32, 64);
        if (half == 0 && l32 < 20) {
            float inv = 1.0f / fmaxf((float)(e - s), 1.0f);
            float2 yr = *reinterpret_cast<const float2*>(&yr40[(size_t)w * 40 + 2 * l32]);
            float vx = ax * inv + yr.x;
            float vy = ay * inv + yr.y;
            *reinterpret_cast<float2*>(&out[(size_t)w * 40 + 2 * l32]) = make_float2(vx, vy);
            sh[wv][2 * l32]     = vx;
            sh[wv][2 * l32 + 1] = vy;
        }
    }
    if (lane == 0) {
        if (w < N) {
            int g = batch[w];
            sg[wv] = g;
            sinv[wv] = 1.0f / fmaxf((float)(gstart[g + 1] - gstart[g]), 1.0f);
        } else {
            sg[wv] = -1;
        }
    }
    __syncthreads();
    // wave 0 flushes: batch is sorted -> typically one graph per block
    if (wv == 0 && lane < 40) {
        int cur = -1;
        float accum = 0.f;
        #pragma unroll
        for (int k = 0; k < 4; ++k) {
            int gk = sg[k];
            if (gk < 0) continue;
            float c = sh[k][lane] * sinv[k];
            if (gk == cur) {
                accum += c;
            } else {
                if (cur >= 0) atomicAdd(&gsum[cur * 40 + lane], accum);
                cur = gk;
                accum = c;
            }
        }
        if (cur >= 0) atomicAdd(&gsum[cur * 40 + lane], accum);
    }
}

extern "C" void kernel_launch(void* const* d_in, const int* in_sizes, int n_in,
                              void* d_out, int out_size, void* d_ws, size_t ws_size,
                              hipStream_t stream) {
    const float* x    = (const float*)d_in[0];
    const int*   ei   = (const int*)d_in[1];
    const int*   batch= (const int*)d_in[2];
    const float* Wl0  = (const float*)d_in[3];
    const float* bl0  = (const float*)d_in[4];
    const float* Wr0  = (const float*)d_in[5];
    const float* Wl1  = (const float*)d_in[6];
    const float* bl1  = (const float*)d_in[7];
    const float* Wr1  = (const float*)d_in[8];
    const float* Wl2  = (const float*)d_in[9];
    const float* bl2  = (const float*)d_in[10];
    const float* Wr2  = (const float*)d_in[11];

    const int N = in_sizes[0] / K_DIM;       // 50000
    const int E = in_sizes[1] / 2;           // 600000
    const int* src = ei;
    const int* dst = ei + E;

    float* out = (float*)d_out;              // h3 [N,40] then g [128,40]
    float* gsum = out + (size_t)N * 40;

    char* w = (char*)d_ws;
    auto alloc = [&](size_t bytes) {
        char* p = w;
        w += (bytes + 255) & ~(size_t)255;
        return p;
    };
    const size_t PL = (size_t)N * K_DIM * 2;  // one bf16 plane = 12.8 MB
    short* aggb  = (short*)alloc(PL);
    short* xb    = (short*)alloc(PL);
    short* h1hi  = (short*)alloc(PL);
    short* h1lo  = (short*)alloc(PL);
    short* ylb   = (short*)alloc((size_t)N * 40 * 2);
    float* yr40  = (float*)alloc((size_t)N * 40 * 4);
    int*   rowptr= (int*)alloc((size_t)(N + 1) * 4);
    int*   deg   = (int*)alloc((size_t)N * 4);
    int*   fillp = (int*)alloc((size_t)N * 4);
    int*   csr   = (int*)alloc((size_t)E * 4);
    int*   counter = (int*)alloc(256);
    int*   gstart= (int*)alloc((size_t)(N_GRAPHS + 1) * 4);
    short* whi   = (short*)alloc(77824 * 2);
    short* wlo   = (short*)alloc(77824 * 2);

    const int NB = (N + 255) / 256;              // 196
    const int initGrid = (77824 + 255) / 256;    // 304 (covers N? no -> see below)
    const int bigGrid  = (N * (K_DIM / 4) + 255) / 256;   // 6250

    // init covers max(N, TOT, N_GRAPHS*40): N=50000 dominates -> 196 blocks? 
    // N=50000 needs 196 blocks; TOT=77824 needs 304. Use 304.
    init_kernel<<<304, 256, 0, stream>>>(Wl0, Wr0, Wl1, Wr1, Wl2, Wr2,
                                         whi, wlo, deg, batch, gstart, counter,
                                         gsum, N);
    xconv_deg<<<bigGrid, 256, 0, stream>>>(x, xb, dst, deg, N, E);
    csr_offsets<<<NB, 256, 0, stream>>>(deg, counter, rowptr, fillp, N);
    fill_kernel<<<(E + 255) / 256, 256, 0, stream>>>(src, dst, fillp, csr, E);

    short* hWl0 = whi;          short* lWl0 = wlo;
    short* hWr0 = whi + 16384;  short* lWr0 = wlo + 16384;
    short* hWl1 = whi + 32768;  short* lWl1 = wlo + 32768;
    short* hWr1 = whi + 49152;  short* lWr1 = wlo + 49152;
    short* hW2  = whi + 65536;  short* lW2  = wlo + 65536;

    const int aggGrid   = (N * 64 + 255) / 256;   // 12500
    const int gemmGrid32= (N + 31) / 32;          // 1563

    // layer 0 (H operand staged from fp32 x directly)
    agg_bf16<<<aggGrid, 256, 0, stream>>>((const unsigned short*)xb, rowptr, deg, csr, aggb, N);
    sage0_mfma<<<gemmGrid32, 256, 0, stream>>>(
        aggb, x, hWl0, lWl0, hWr0, lWr0, bl0, h1hi, h1lo, N);
    // layer 1 + layer 2 fused (h1hi doubles as the gather table: h1 >= 0)
    agg_bf16<<<aggGrid, 256, 0, stream>>>((const unsigned short*)h1hi, rowptr, deg, csr, aggb, N);
    sage1_gemm80<<<gemmGrid32, 256, 0, stream>>>(
        aggb, h1hi, h1lo, hWl1, lWl1, hWr1, lWr1, bl1, hW2, lW2, bl2, ylb, yr40, N);
    // agg40 + pool
    agg40_pool<<<aggGrid, 256, 0, stream>>>((const unsigned int*)ylb, yr40,
                                            rowptr, deg, csr, batch, gstart, out, gsum, N);
}

// Round 15
// 290.828 us; speedup vs baseline: 1.0192x; 1.0192x over previous
//
#include <hip/hip_runtime.h>
#include <hip/hip_bf16.h>

// ---------------------------------------------------------------------------
// GraphSAGE 3-layer + global mean pool, fp32 in/out.
//   layer: agg = mean_{e:dst=n} relu(h[src_e]);  h' = agg@Wl^T + bl + h@Wr^T
// R1-R14: 810 -> 336us. R15 coop frontend REGRESSED. R16 neutral.
// R17/18 agg40 ILP -> 326.8. R19 csr_offsets -> 325. R20 neutral.
// R21 layer1+2 fuse. R22-R25 tile/TLP/barrier probes ~neutral.
// R26: fragment-linear weight packing (B loads were 16-way line-amplified
//   -> ~5M serialized L2 requests): 325 -> 293.3us. BEST MEASURED.
// R27: sage0 BM=32 port: neutral (294.4). R28: xconv/deg overlap: neutral
//   (296.4). Plateau cluster {293.3, 294.4, 296.4} -> composite floor:
//   gathers at 5.7TB/s BW floor, GEMMs at latency floor (6 probe rounds),
//   fill/deg at scatter service floor, harness fills untouchable.
// R29 (this round): consolidation — exact revert to the best-measured R26
//   configuration. No new mechanisms. Expect ~293-296; then ROOFLINE.
// ---------------------------------------------------------------------------

#define NODES 50000
#define K_DIM 128
#define N_GRAPHS 128

typedef __attribute__((ext_vector_type(8))) short short8;
typedef __attribute__((ext_vector_type(4))) short short4v;
typedef __attribute__((ext_vector_type(4))) float f32x4;

__device__ inline short f2bf(float f) {
    unsigned u = __builtin_bit_cast(unsigned, f);
    u += 0x7FFFu + ((u >> 16) & 1u);          // RNE
    return (short)(u >> 16);
}
__device__ inline float bf2f(short h) {
    unsigned u = ((unsigned)(unsigned short)h) << 16;
    return __builtin_bit_cast(float, u);
}
__device__ inline float blo(unsigned u) { return __builtin_bit_cast(float, u << 16); }
__device__ inline float bhi(unsigned u) { return __builtin_bit_cast(float, u & 0xFFFF0000u); }
// pack: bits[15:0]=hi bf16, bits[31:16]=lo bf16
__device__ inline unsigned hilo_pack(float f) {
    short h = f2bf(f);
    short l = f2bf(f - bf2f(h));
    return ((unsigned)(unsigned short)h) | (((unsigned)(unsigned short)l) << 16);
}

// ------ init: zero deg+gsum+counter + FRAGMENT-PACKED wconv + gstart + xb --
// Phase-1 planes (4x 128x128): packed idx = ((wave*2+nt)*4+kc)*512 +
//   lane*8 + e  with n=wave*32+nt*16+(lane&15), k=kc*32+(lane>>4)*8+e.
// W2 plane (12288): packed idx = (nt2*4+kc)*512 + lane*8 + e, tiles 20..23
//   zero-padded; n=nt2*16+(lane&15) (<80), same k formula.
__global__ void init_kernel(const float* __restrict__ w0, const float* __restrict__ w1,
                            const float* __restrict__ w2, const float* __restrict__ w3,
                            const float* __restrict__ w4, const float* __restrict__ w5,
                            short* __restrict__ whi, short* __restrict__ wlo,
                            int* __restrict__ deg, const int* __restrict__ batch,
                            int* __restrict__ gstart, int* __restrict__ counter,
                            const float* __restrict__ x, short* __restrict__ xb,
                            float* __restrict__ gsum, int N) {
    int idx = blockIdx.x * 256 + threadIdx.x;
    if (idx < N * (K_DIM / 4)) {
        float4 v = reinterpret_cast<const float4*>(x)[idx];
        short4v b;
        b[0] = f2bf(fmaxf(v.x, 0.f));
        b[1] = f2bf(fmaxf(v.y, 0.f));
        b[2] = f2bf(fmaxf(v.z, 0.f));
        b[3] = f2bf(fmaxf(v.w, 0.f));
        *reinterpret_cast<short4v*>(&xb[idx * 4]) = b;
    }
    if (idx < N) deg[idx] = 0;
    if (idx < N_GRAPHS * 40) gsum[idx] = 0.f;
    if (idx == 0) *counter = 0;
    const int TOT = 4 * 16384 + 96 * 128;   // 77824
    if (idx < TOT) {
        float v;
        if (idx < 65536) {
            int m = idx >> 14, i2 = idx & 16383;
            const float* W = (m == 0) ? w0 : (m == 1) ? w1 : (m == 2) ? w2 : w3;
            int t1 = i2 >> 9, rem = i2 & 511;
            int lane = rem >> 3, e = rem & 7;
            int wv_ = t1 >> 3, nt = (t1 >> 2) & 1, kc = t1 & 3;
            int quad = lane >> 4, l15 = lane & 15;
            int n = wv_ * 32 + nt * 16 + l15;
            int k = kc * 32 + quad * 8 + e;
            v = W[n * 128 + k];
        } else {
            int i2 = idx - 65536;            // 0..12287
            int t2 = i2 >> 9, rem = i2 & 511;
            int lane = rem >> 3, e = rem & 7;
            int nt2 = t2 >> 2, kc = t2 & 3;
            int quad = lane >> 4, l15 = lane & 15;
            int n = nt2 * 16 + l15;
            int k = kc * 32 + quad * 8 + e;
            if (t2 < 20) {
                v = (n < 40) ? w4[n * 128 + k] : w5[(n - 40) * 128 + k];
            } else {
                v = 0.f;
            }
        }
        unsigned p = hilo_pack(v);
        whi[idx] = (short)(p & 0xFFFFu);
        wlo[idx] = (short)(p >> 16);
    }
    if (idx <= N_GRAPHS) {
        int g = idx;
        int lo = 0, hi = N;
        while (lo < hi) {
            int mid = (lo + hi) >> 1;
            if (batch[mid] < g) lo = mid + 1; else hi = mid;
        }
        gstart[g] = lo;
    }
}

// ---------------- CSR build ----------------
__global__ void deg_kernel(const int* __restrict__ dst, int* __restrict__ deg, int E) {
    int e = blockIdx.x * blockDim.x + threadIdx.x;
    if (e < E) atomicAdd(&deg[dst[e]], 1);
}

// single-dispatch offsets: block-local scan + atomic global base.
__global__ void csr_offsets(const int* __restrict__ deg, int* __restrict__ counter,
                            int* __restrict__ rowptr, int* __restrict__ fillpos, int N) {
    const int tid = threadIdx.x, lane = tid & 63, wv = tid >> 6;
    int i = blockIdx.x * 256 + tid;
    int v = (i < N) ? deg[i] : 0;
    int incl = v;
    #pragma unroll
    for (int off = 1; off < 64; off <<= 1) {
        int t = __shfl_up(incl, off, 64);
        if (lane >= off) incl += t;
    }
    __shared__ int ws[4];
    __shared__ int sbase;
    if (lane == 63) ws[wv] = incl;
    __syncthreads();
    if (tid == 0) sbase = atomicAdd(counter, ws[0] + ws[1] + ws[2] + ws[3]);
    __syncthreads();
    int add = sbase;
    for (int k = 0; k < wv; ++k) add += ws[k];
    int excl = add + incl - v;
    if (i < N) { rowptr[i] = excl; fillpos[i] = excl; }
}

__global__ void fill_kernel(const int* __restrict__ src, const int* __restrict__ dst,
                            int* __restrict__ fillpos, int* __restrict__ csr_src, int E) {
    int e = blockIdx.x * blockDim.x + threadIdx.x;
    if (e < E) {
        int p = atomicAdd(&fillpos[dst[e]], 1);
        csr_src[p] = src[e];
    }
}

// ------- aggregation from bf16 table (128-dim) -> bf16 mean ----------------
__global__ void agg_bf16(const unsigned short* __restrict__ hb,
                         const int* __restrict__ rowptr, const int* __restrict__ deg,
                         const int* __restrict__ csr_src,
                         short* __restrict__ aggb, int N) {
    int w = (blockIdx.x * blockDim.x + threadIdx.x) >> 6;
    if (w >= N) return;
    int lane = threadIdx.x & 63;
    int slot = lane >> 4, l16 = lane & 15;
    int s = rowptr[w];
    int e = s + deg[w];
    const uint4* T = reinterpret_cast<const uint4*>(hb);   // 16 uint4 per row
    float2 a0 = make_float2(0.f, 0.f), a1 = a0, a2 = a0, a3 = a0;
    int i = s + slot;
    for (; i + 4 < e; i += 8) {
        uint4 va = T[(size_t)csr_src[i] * 16 + l16];
        uint4 vb = T[(size_t)csr_src[i + 4] * 16 + l16];
        a0.x += blo(va.x) + blo(vb.x); a0.y += bhi(va.x) + bhi(vb.x);
        a1.x += blo(va.y) + blo(vb.y); a1.y += bhi(va.y) + bhi(vb.y);
        a2.x += blo(va.z) + blo(vb.z); a2.y += bhi(va.z) + bhi(vb.z);
        a3.x += blo(va.w) + blo(vb.w); a3.y += bhi(va.w) + bhi(vb.w);
    }
    for (; i < e; i += 4) {
        uint4 va = T[(size_t)csr_src[i] * 16 + l16];
        a0.x += blo(va.x); a0.y += bhi(va.x);
        a1.x += blo(va.y); a1.y += bhi(va.y);
        a2.x += blo(va.z); a2.y += bhi(va.z);
        a3.x += blo(va.w); a3.y += bhi(va.w);
    }
    #pragma unroll
    for (int off = 16; off <= 32; off <<= 1) {
        a0.x += __shfl_xor(a0.x, off, 64); a0.y += __shfl_xor(a0.y, off, 64);
        a1.x += __shfl_xor(a1.x, off, 64); a1.y += __shfl_xor(a1.y, off, 64);
        a2.x += __shfl_xor(a2.x, off, 64); a2.y += __shfl_xor(a2.y, off, 64);
        a3.x += __shfl_xor(a3.x, off, 64); a3.y += __shfl_xor(a3.y, off, 64);
    }
    if (slot == 0) {
        float inv = 1.0f / fmaxf((float)(e - s), 1.0f);
        short8 b;
        b[0] = f2bf(a0.x * inv); b[1] = f2bf(a0.y * inv);
        b[2] = f2bf(a1.x * inv); b[3] = f2bf(a1.y * inv);
        b[4] = f2bf(a2.x * inv); b[5] = f2bf(a2.y * inv);
        b[6] = f2bf(a3.x * inv); b[7] = f2bf(a3.y * inv);
        *reinterpret_cast<short8*>(&aggb[(size_t)w * K_DIM + l16 * 8]) = b;
    }
}

// --------- layer-0 MFMA GEMM: out = aggb@Wl^T + bl + x@Wr^T, relu ----------
// R26 form: fragment-packed B loads (1KB coalesced per wave-load).
__global__ __launch_bounds__(256) void sage0_mfma(
        const short* __restrict__ Ab_in, const float* __restrict__ Xf,
        const short* __restrict__ Bhl, const short* __restrict__ Bll,
        const short* __restrict__ Bhr, const short* __restrict__ Blr,
        const float* __restrict__ bl,
        short* __restrict__ outHi, short* __restrict__ outLo, int N) {
    constexpr int BM = 64;
    constexpr int LSTR = 40;
    const int tid = threadIdx.x;
    const int lane = tid & 63;
    const int wave = tid >> 6;
    const int l15 = lane & 15;
    const int quad = lane >> 4;
    const int m0 = blockIdx.x * BM;
    const int srow = tid >> 2, sc8 = tid & 3;

    __shared__ __align__(16) short Ab [BM * LSTR];
    __shared__ __align__(16) short Ahi[BM * LSTR];
    __shared__ __align__(16) short Alo[BM * LSTR];

    f32x4 acc[4][2];
    #pragma unroll
    for (int i = 0; i < 4; ++i)
        #pragma unroll
        for (int j = 0; j < 2; ++j) acc[i][j] = (f32x4){0.f, 0.f, 0.f, 0.f};

    const short8 zero8 = (short8){0, 0, 0, 0, 0, 0, 0, 0};
    const int sm = m0 + srow;

    for (int k0 = 0; k0 < K_DIM; k0 += 32) {
        const int kc = k0 >> 5;
        __syncthreads();
        {
            short8 va = zero8, vh = zero8, vl = zero8;
            if (sm < N) {
                va = *reinterpret_cast<const short8*>(Ab_in + (size_t)sm * K_DIM + k0 + sc8 * 8);
                const float* xp = Xf + (size_t)sm * K_DIM + k0 + sc8 * 8;
                float4 f0 = *reinterpret_cast<const float4*>(xp);
                float4 f1 = *reinterpret_cast<const float4*>(xp + 4);
                float fv[8] = {f0.x, f0.y, f0.z, f0.w, f1.x, f1.y, f1.z, f1.w};
                #pragma unroll
                for (int j = 0; j < 8; ++j) {
                    unsigned p = hilo_pack(fv[j]);
                    vh[j] = (short)(p & 0xFFFFu);
                    vl[j] = (short)(p >> 16);
                }
            }
            *reinterpret_cast<short8*>(&Ab [srow * LSTR + sc8 * 8]) = va;
            *reinterpret_cast<short8*>(&Ahi[srow * LSTR + sc8 * 8]) = vh;
            *reinterpret_cast<short8*>(&Alo[srow * LSTR + sc8 * 8]) = vl;
        }
        short8 bhl_[2], bll_[2], bhr_[2], blr_[2];
        #pragma unroll
        for (int nt = 0; nt < 2; ++nt) {
            size_t base = ((size_t)(((wave * 2 + nt) * 4 + kc) * 64 + lane)) * 8;
            bhl_[nt] = *reinterpret_cast<const short8*>(Bhl + base);
            bll_[nt] = *reinterpret_cast<const short8*>(Bll + base);
            bhr_[nt] = *reinterpret_cast<const short8*>(Bhr + base);
            blr_[nt] = *reinterpret_cast<const short8*>(Blr + base);
        }
        __syncthreads();
        #pragma unroll
        for (int mt = 0; mt < 4; ++mt) {
            int row = mt * 16 + l15;
            short8 ab = *reinterpret_cast<const short8*>(&Ab [row * LSTR + quad * 8]);
            short8 ah = *reinterpret_cast<const short8*>(&Ahi[row * LSTR + quad * 8]);
            short8 ao = *reinterpret_cast<const short8*>(&Alo[row * LSTR + quad * 8]);
            #pragma unroll
            for (int nt = 0; nt < 2; ++nt) {
                acc[mt][nt] = __builtin_amdgcn_mfma_f32_16x16x32_bf16(ab, bhl_[nt], acc[mt][nt], 0, 0, 0);
                acc[mt][nt] = __builtin_amdgcn_mfma_f32_16x16x32_bf16(ab, bll_[nt], acc[mt][nt], 0, 0, 0);
                acc[mt][nt] = __builtin_amdgcn_mfma_f32_16x16x32_bf16(ah, bhr_[nt], acc[mt][nt], 0, 0, 0);
                acc[mt][nt] = __builtin_amdgcn_mfma_f32_16x16x32_bf16(ah, blr_[nt], acc[mt][nt], 0, 0, 0);
                acc[mt][nt] = __builtin_amdgcn_mfma_f32_16x16x32_bf16(ao, bhr_[nt], acc[mt][nt], 0, 0, 0);
            }
        }
    }

    // ---- epilogue: relu(acc + bias) -> hi/lo planes ----
    #pragma unroll
    for (int mt = 0; mt < 4; ++mt) {
        #pragma unroll
        for (int nt = 0; nt < 2; ++nt) {
            int col = wave * 32 + nt * 16 + l15;
            float b = bl[col];
            #pragma unroll
            for (int reg = 0; reg < 4; ++reg) {
                int row = m0 + mt * 16 + quad * 4 + reg;
                if (row < N) {
                    float v = fmaxf(acc[mt][nt][reg] + b, 0.f);
                    unsigned p = hilo_pack(v);
                    outHi[(size_t)row * K_DIM + col] = (short)(p & 0xFFFFu);
                    outLo[(size_t)row * K_DIM + col] = (short)(p >> 16);
                }
            }
        }
    }
}

// --------- fused layer-1 + layer-2 GEMM (R25 structure + packed B) --------
__global__ __launch_bounds__(256) void sage1_gemm80(
        const short* __restrict__ Ab_in,
        const short* __restrict__ Hhi_in, const short* __restrict__ Hlo_in,
        const short* __restrict__ Bhl, const short* __restrict__ Bll,
        const short* __restrict__ Bhr, const short* __restrict__ Blr,
        const float* __restrict__ bl,
        const short* __restrict__ B2h, const short* __restrict__ B2l,
        const float* __restrict__ b2,
        short* __restrict__ ylb, float* __restrict__ yr40, int N) {
    constexpr int BM = 32;
    constexpr int LSTA = 136;    // full-K row stride (shorts), 272B
    const int tid = threadIdx.x;
    const int lane = tid & 63;
    const int wave = tid >> 6;
    const int l15 = lane & 15;
    const int quad = lane >> 4;
    const int m0 = blockIdx.x * BM;

    __shared__ __align__(16) short SH[3 * BM * LSTA];   // 25.5 KB
    short* AbL = SH;
    short* AhL = SH + BM * LSTA;
    short* AlL = SH + 2 * BM * LSTA;
    // aliased after phase 1:
    short* H2h = SH;
    short* H2l = SH + BM * LSTA;

    f32x4 acc[2][2];
    #pragma unroll
    for (int i = 0; i < 2; ++i)
        #pragma unroll
        for (int j = 0; j < 2; ++j) acc[i][j] = (f32x4){0.f, 0.f, 0.f, 0.f};

    const short8 zero8 = (short8){0, 0, 0, 0, 0, 0, 0, 0};

    // ---- stage: ALL of A (3 planes x 32x128) in one shot ----
    {
        const int srow = tid >> 3;          // 0..31
        const int c0 = (tid & 7) * 16;      // 0,16,...,112
        const int sm = m0 + srow;
        short8 a0 = zero8, a1 = zero8, h0 = zero8, h1 = zero8, l0 = zero8, l1 = zero8;
        if (sm < N) {
            const short* pa = Ab_in  + (size_t)sm * K_DIM + c0;
            const short* ph = Hhi_in + (size_t)sm * K_DIM + c0;
            const short* pl = Hlo_in + (size_t)sm * K_DIM + c0;
            a0 = *reinterpret_cast<const short8*>(pa);
            a1 = *reinterpret_cast<const short8*>(pa + 8);
            h0 = *reinterpret_cast<const short8*>(ph);
            h1 = *reinterpret_cast<const short8*>(ph + 8);
            l0 = *reinterpret_cast<const short8*>(pl);
            l1 = *reinterpret_cast<const short8*>(pl + 8);
        }
        *reinterpret_cast<short8*>(&AbL[srow * LSTA + c0])     = a0;
        *reinterpret_cast<short8*>(&AbL[srow * LSTA + c0 + 8]) = a1;
        *reinterpret_cast<short8*>(&AhL[srow * LSTA + c0])     = h0;
        *reinterpret_cast<short8*>(&AhL[srow * LSTA + c0 + 8]) = h1;
        *reinterpret_cast<short8*>(&AlL[srow * LSTA + c0])     = l0;
        *reinterpret_cast<short8*>(&AlL[srow * LSTA + c0 + 8]) = l1;
    }
    __syncthreads();   // [1]

    // ---- phase 1: 4 unfenced k-steps, packed B (coalesced) ----
    #pragma unroll
    for (int kc = 0; kc < 4; ++kc) {
        const int k0 = kc * 32;
        short8 bhl_[2], bll_[2], bhr_[2], blr_[2];
        #pragma unroll
        for (int nt = 0; nt < 2; ++nt) {
            size_t base = ((size_t)(((wave * 2 + nt) * 4 + kc) * 64 + lane)) * 8;
            bhl_[nt] = *reinterpret_cast<const short8*>(Bhl + base);
            bll_[nt] = *reinterpret_cast<const short8*>(Bll + base);
            bhr_[nt] = *reinterpret_cast<const short8*>(Bhr + base);
            blr_[nt] = *reinterpret_cast<const short8*>(Blr + base);
        }
        #pragma unroll
        for (int mt = 0; mt < 2; ++mt) {
            int row = mt * 16 + l15;
            short8 ab = *reinterpret_cast<const short8*>(&AbL[row * LSTA + k0 + quad * 8]);
            short8 ah = *reinterpret_cast<const short8*>(&AhL[row * LSTA + k0 + quad * 8]);
            short8 ao = *reinterpret_cast<const short8*>(&AlL[row * LSTA + k0 + quad * 8]);
            #pragma unroll
            for (int nt = 0; nt < 2; ++nt) {
                acc[mt][nt] = __builtin_amdgcn_mfma_f32_16x16x32_bf16(ab, bhl_[nt], acc[mt][nt], 0, 0, 0);
                acc[mt][nt] = __builtin_amdgcn_mfma_f32_16x16x32_bf16(ab, bll_[nt], acc[mt][nt], 0, 0, 0);
                acc[mt][nt] = __builtin_amdgcn_mfma_f32_16x16x32_bf16(ah, bhr_[nt], acc[mt][nt], 0, 0, 0);
                acc[mt][nt] = __builtin_amdgcn_mfma_f32_16x16x32_bf16(ah, blr_[nt], acc[mt][nt], 0, 0, 0);
                acc[mt][nt] = __builtin_amdgcn_mfma_f32_16x16x32_bf16(ao, bhr_[nt], acc[mt][nt], 0, 0, 0);
            }
        }
    }

    __syncthreads();   // [2] all phase-1 LDS reads done; A buffer now dead

    // ---- h2 = relu(acc+bias) -> LDS (aliased), full 32x128 ----
    #pragma unroll
    for (int mt = 0; mt < 2; ++mt) {
        #pragma unroll
        for (int nt = 0; nt < 2; ++nt) {
            int col = wave * 32 + nt * 16 + l15;
            float b = bl[col];
            #pragma unroll
            for (int reg = 0; reg < 4; ++reg) {
                int row = mt * 16 + quad * 4 + reg;
                float v = fmaxf(acc[mt][nt][reg] + b, 0.f);
                unsigned p = hilo_pack(v);
                H2h[row * LSTA + col] = (short)(p & 0xFFFFu);
                H2l[row * LSTA + col] = (short)(p >> 16);
            }
        }
    }
    __syncthreads();   // [3]

    // ---- phase 2: 4 unfenced kc-steps from H2, packed B2 ----
    const int rg = wave >> 1, ch = wave & 1;
    const int NT = ch ? 2 : 3;
    const int ntb = ch ? 3 : 0;
    f32x4 c2[3];
    #pragma unroll
    for (int j = 0; j < 3; ++j) c2[j] = (f32x4){0.f, 0.f, 0.f, 0.f};
    const int arow = rg * 16 + l15;

    #pragma unroll
    for (int kc = 0; kc < 4; ++kc) {
        const int k0 = kc * 32;
        short8 ah = *reinterpret_cast<const short8*>(&H2h[arow * LSTA + k0 + quad * 8]);
        short8 ao = *reinterpret_cast<const short8*>(&H2l[arow * LSTA + k0 + quad * 8]);
        for (int j = 0; j < NT; ++j) {
            size_t base = ((size_t)(((ntb + j) * 4 + kc) * 64 + lane)) * 8;
            short8 bh = *reinterpret_cast<const short8*>(B2h + base);
            short8 bo = *reinterpret_cast<const short8*>(B2l + base);
            c2[j] = __builtin_amdgcn_mfma_f32_16x16x32_bf16(ah, bh, c2[j], 0, 0, 0);
            c2[j] = __builtin_amdgcn_mfma_f32_16x16x32_bf16(ah, bo, c2[j], 0, 0, 0);
            c2[j] = __builtin_amdgcn_mfma_f32_16x16x32_bf16(ao, bh, c2[j], 0, 0, 0);
        }
    }

    // ---- epilogue 2: ylb (cols 0-39, bf16), yr40 (cols 40-79, +bias) ----
    for (int j = 0; j < NT; ++j) {
        int col = (ntb + j) * 16 + l15;
        #pragma unroll
        for (int reg = 0; reg < 4; ++reg) {
            int row = m0 + rg * 16 + quad * 4 + reg;
            if (row < N) {
                float v = c2[j][reg];
                if (col < 40) {
                    ylb[(size_t)row * 40 + col] = f2bf(v);
                } else {
                    yr40[(size_t)row * 40 + (col - 40)] = v + b2[col - 40];
                }
            }
        }
    }
}

// ------- agg40 + pool: out[n] = mean_e ylb[src_e] + yr40[n];
//         gsum[g] += out[n]/cnt(g). --------------------------------------
__global__ __launch_bounds__(256) void agg40_pool(
        const unsigned int* __restrict__ ylbu, const float* __restrict__ yr40,
        const int* __restrict__ rowptr, const int* __restrict__ deg,
        const int* __restrict__ csr_src,
        const int* __restrict__ batch, const int* __restrict__ gstart,
        float* __restrict__ out, float* __restrict__ gsum, int N) {
    const int w = (blockIdx.x * blockDim.x + threadIdx.x) >> 6;
    const int lane = threadIdx.x & 63;
    const int wv = threadIdx.x >> 6;
    const int half = lane >> 5, l32 = lane & 31;
    __shared__ float sh[4][40];
    __shared__ int sg[4];
    __shared__ float sinv[4];

    if (w < N) {
        int s = rowptr[w], e = s + deg[w];
        float ax = 0.f, ay = 0.f;
        if (l32 < 20) {
            int i = s + half;
            for (; i + 6 < e; i += 8) {
                int s0 = csr_src[i], s1 = csr_src[i + 2], s2 = csr_src[i + 4], s3 = csr_src[i + 6];
                unsigned v0 = ylbu[(size_t)s0 * 20 + l32];
                unsigned v1 = ylbu[(size_t)s1 * 20 + l32];
                unsigned v2 = ylbu[(size_t)s2 * 20 + l32];
                unsigned v3 = ylbu[(size_t)s3 * 20 + l32];
                ax += (blo(v0) + blo(v1)) + (blo(v2) + blo(v3));
                ay += (bhi(v0) + bhi(v1)) + (bhi(v2) + bhi(v3));
            }
            for (; i < e; i += 2) {
                unsigned v0 = ylbu[(size_t)csr_src[i] * 20 + l32];
                ax += blo(v0); ay += bhi(v0);
            }
        }
        ax += __shfl_xor(ax, 32, 64);
        ay += __shfl_xor(ay, 32, 64);
        if (half == 0 && l32 < 20) {
            float inv = 1.0f / fmaxf((float)(e - s), 1.0f);
            float2 yr = *reinterpret_cast<const float2*>(&yr40[(size_t)w * 40 + 2 * l32]);
            float vx = ax * inv + yr.x;
            float vy = ay * inv + yr.y;
            *reinterpret_cast<float2*>(&out[(size_t)w * 40 + 2 * l32]) = make_float2(vx, vy);
            sh[wv][2 * l32]     = vx;
            sh[wv][2 * l32 + 1] = vy;
        }
    }
    if (lane == 0) {
        if (w < N) {
            int g = batch[w];
            sg[wv] = g;
            sinv[wv] = 1.0f / fmaxf((float)(gstart[g + 1] - gstart[g]), 1.0f);
        } else {
            sg[wv] = -1;
        }
    }
    __syncthreads();
    // wave 0 flushes: batch is sorted -> typically one graph per block
    if (wv == 0 && lane < 40) {
        int cur = -1;
        float accum = 0.f;
        #pragma unroll
        for (int k = 0; k < 4; ++k) {
            int gk = sg[k];
            if (gk < 0) continue;
            float c = sh[k][lane] * sinv[k];
            if (gk == cur) {
                accum += c;
            } else {
                if (cur >= 0) atomicAdd(&gsum[cur * 40 + lane], accum);
                cur = gk;
                accum = c;
            }
        }
        if (cur >= 0) atomicAdd(&gsum[cur * 40 + lane], accum);
    }
}

extern "C" void kernel_launch(void* const* d_in, const int* in_sizes, int n_in,
                              void* d_out, int out_size, void* d_ws, size_t ws_size,
                              hipStream_t stream) {
    const float* x    = (const float*)d_in[0];
    const int*   ei   = (const int*)d_in[1];
    const int*   batch= (const int*)d_in[2];
    const float* Wl0  = (const float*)d_in[3];
    const float* bl0  = (const float*)d_in[4];
    const float* Wr0  = (const float*)d_in[5];
    const float* Wl1  = (const float*)d_in[6];
    const float* bl1  = (const float*)d_in[7];
    const float* Wr1  = (const float*)d_in[8];
    const float* Wl2  = (const float*)d_in[9];
    const float* bl2  = (const float*)d_in[10];
    const float* Wr2  = (const float*)d_in[11];

    const int N = in_sizes[0] / K_DIM;       // 50000
    const int E = in_sizes[1] / 2;           // 600000
    const int* src = ei;
    const int* dst = ei + E;

    float* out = (float*)d_out;              // h3 [N,40] then g [128,40]
    float* gsum = out + (size_t)N * 40;

    char* w = (char*)d_ws;
    auto alloc = [&](size_t bytes) {
        char* p = w;
        w += (bytes + 255) & ~(size_t)255;
        return p;
    };
    const size_t PL = (size_t)N * K_DIM * 2;  // one bf16 plane = 12.8 MB
    short* aggb  = (short*)alloc(PL);
    short* xb    = (short*)alloc(PL);
    short* h1hi  = (short*)alloc(PL);
    short* h1lo  = (short*)alloc(PL);
    short* ylb   = (short*)alloc((size_t)N * 40 * 2);
    float* yr40  = (float*)alloc((size_t)N * 40 * 4);
    int*   rowptr= (int*)alloc((size_t)(N + 1) * 4);
    int*   deg   = (int*)alloc((size_t)N * 4);
    int*   fillp = (int*)alloc((size_t)N * 4);
    int*   csr   = (int*)alloc((size_t)E * 4);
    int*   counter = (int*)alloc(256);
    int*   gstart= (int*)alloc((size_t)(N_GRAPHS + 1) * 4);
    short* whi   = (short*)alloc(77824 * 2);
    short* wlo   = (short*)alloc(77824 * 2);

    const int NB = (N + 255) / 256;              // 196
    const int initGrid = (N * (K_DIM / 4) + 255) / 256;   // 6250

    init_kernel<<<initGrid, 256, 0, stream>>>(Wl0, Wr0, Wl1, Wr1, Wl2, Wr2,
                                              whi, wlo, deg, batch, gstart, counter,
                                              x, xb, gsum, N);
    deg_kernel<<<(E + 255) / 256, 256, 0, stream>>>(dst, deg, E);
    csr_offsets<<<NB, 256, 0, stream>>>(deg, counter, rowptr, fillp, N);
    fill_kernel<<<(E + 255) / 256, 256, 0, stream>>>(src, dst, fillp, csr, E);

    short* hWl0 = whi;          short* lWl0 = wlo;
    short* hWr0 = whi + 16384;  short* lWr0 = wlo + 16384;
    short* hWl1 = whi + 32768;  short* lWl1 = wlo + 32768;
    short* hWr1 = whi + 49152;  short* lWr1 = wlo + 49152;
    short* hW2  = whi + 65536;  short* lW2  = wlo + 65536;

    const int aggGrid   = (N * 64 + 255) / 256;   // 12500
    const int gemmGrid  = (N + 63) / 64;          // 782
    const int gemmGrid32= (N + 31) / 32;          // 1563

    // layer 0 (H operand staged from fp32 x directly)
    agg_bf16<<<aggGrid, 256, 0, stream>>>((const unsigned short*)xb, rowptr, deg, csr, aggb, N);
    sage0_mfma<<<gemmGrid, 256, 0, stream>>>(
        aggb, x, hWl0, lWl0, hWr0, lWr0, bl0, h1hi, h1lo, N);
    // layer 1 + layer 2 fused (h1hi doubles as the gather table: h1 >= 0)
    agg_bf16<<<aggGrid, 256, 0, stream>>>((const unsigned short*)h1hi, rowptr, deg, csr, aggb, N);
    sage1_gemm80<<<gemmGrid32, 256, 0, stream>>>(
        aggb, h1hi, h1lo, hWl1, lWl1, hWr1, lWr1, bl1, hW2, lW2, bl2, ylb, yr40, N);
    // agg40 + pool
    agg40_pool<<<aggGrid, 256, 0, stream>>>((const unsigned int*)ylb, yr40,
                                            rowptr, deg, csr, batch, gstart, out, gsum, N);
}